// Round 1
// baseline (3371.291 us; speedup 1.0000x reference)
//
#include <hip/hip_runtime.h>

typedef _Float16 h2f __attribute__((ext_vector_type(2)));
typedef _Float16 f16x8 __attribute__((ext_vector_type(8)));
typedef float f32x4 __attribute__((ext_vector_type(4)));
typedef unsigned int u32;
typedef unsigned short u16;

#define B_ 128
#define S_ 1024
#define I_ 256
#define H_ 512
#define O_ 256
#define IH_ 768

#if __has_builtin(__builtin_amdgcn_fdot2)
__device__ __forceinline__ float fdot2u(u32 a, u32 b, float c) {
    return __builtin_amdgcn_fdot2(__builtin_bit_cast(h2f, a),
                                  __builtin_bit_cast(h2f, b), c, false);
}
#else
__device__ __forceinline__ float fdot2u(u32 a, u32 b, float c) {
    h2f av = __builtin_bit_cast(h2f, a), bv = __builtin_bit_cast(h2f, b);
    return c + (float)av.x * (float)bv.x + (float)av.y * (float)bv.y;
}
#endif

__device__ __forceinline__ u32 pack2(float x, float y) {
    return __builtin_bit_cast(u32, __builtin_amdgcn_cvt_pkrtz(x, y));
}
__device__ __forceinline__ u16 f2h(float x) { return __builtin_bit_cast(u16, (_Float16)x); }
__device__ __forceinline__ float h2f_(u16 x) { return (float)__builtin_bit_cast(_Float16, x); }

__device__ __forceinline__ float tanh_fast(float x) {
    float e = __expf(-2.f * fabsf(x));     // e in (0,1] -- no overflow path
    float r = (1.f - e) / (1.f + e);
    return copysignf(r, x);
}

// MFMA helper (phase 1): D = A(16x32)*B(32x16)+C, f16 in / f32 acc.
// Verified layouts (m89/m91): A[m=lane&15][k=(lane>>4)*8+j],
// B[k=(lane>>4)*8+j][n=lane&15], C/D col=lane&15 row=(lane>>4)*4+reg.
__device__ __forceinline__ f32x4 mfx(uint4 a, uint4 b, f32x4 c) {
    return __builtin_amdgcn_mfma_f32_16x16x32_f16(
        __builtin_bit_cast(f16x8, a), __builtin_bit_cast(f16x8, b), c, 0, 0, 0);
}
__device__ __forceinline__ f32x4 mf(uint4 a, const uint4* bp, f32x4 c) {
    uint4 b = *bp;
    return mfx(a, b, c);
}

#define REP8(X)  X(0) X(1) X(2) X(3) X(4) X(5) X(6) X(7)
#define REP16(X) REP8(X) X(8) X(9) X(10) X(11) X(12) X(13) X(14) X(15)

// phase-2 split-K slab schedule (32 slabs per thread = half a column):
//   offsets  0..12 : resident in VGPRs (13 x uint4 = 52 regs)
//   offsets 13..15 : LDS-resident (3 x 1024 x 16B = 48 KB, filled once)
//   offsets 16..31 : streamed from L2 each step, four 4-deep chunks
#define RESOFFS(X) X(0) X(1) X(2) X(3) X(4) X(5) X(6) X(7) X(8) X(9) X(10) X(11) X(12)
#define RES_A(X) X(0) X(1) X(2) X(3) X(4) X(5)
#define RES_B(X) X(6) X(7) X(8) X(9) X(10) X(11) X(12)
#define CH_A(X) X(16) X(17) X(18) X(19)
#define CH_B(X) X(20) X(21) X(22) X(23)
#define CH_C(X) X(24) X(25) X(26) X(27)
#define CH_D(X) X(28) X(29) X(30) X(31)
#define LDS3(X) X(0) X(1) X(2)

// ---------------------------------------------------------------------------
// Workspace layout (bytes):
//   wxb4 @ 0      : 16384 uint4 (256 KB)  Wx octets [q 0..31][col 0..511]
//                   octet q of col c = W[c][q*8 .. q*8+7] as f16
//   whb4 @ 256 KB : 32768 uint4 (512 KB)  Wh octets [q 0..63][n 0..511]
//                   octet q of col n = W[n][256+q*8 .. +7] as f16
//   pre  @ 1 MB   : 128*1024*512 f16 (128 MB)
// ---------------------------------------------------------------------------
#define WXB_OFF 0
#define WHB_OFF (256u << 10)
#define PRE_OFF (1u << 20)

__global__ __launch_bounds__(256) void k_convert(const float* __restrict__ W,
                                                 uint4* __restrict__ wxb4,
                                                 uint4* __restrict__ whb4) {
    int idx = blockIdx.x * 256 + threadIdx.x;       // 0..49151
    if (idx < 16384) {                               // wxb: q = idx>>9 (0..31)
        int q = idx >> 9, col = idx & 511;
        const float4* r = (const float4*)(W + (long)col * IH_ + q * 8);
        float4 u = r[0], v = r[1];
        wxb4[idx] = (uint4){pack2(u.x, u.y), pack2(u.z, u.w),
                            pack2(v.x, v.y), pack2(v.z, v.w)};
    } else {                                         // whb: q = 0..63
        int i2 = idx - 16384;
        int q = i2 >> 9, n = i2 & 511;
        const float4* r = (const float4*)(W + (long)n * IH_ + I_ + q * 8);
        float4 u = r[0], v = r[1];
        whb4[i2] = (uint4){pack2(u.x, u.y), pack2(u.z, u.w),
                           pack2(v.x, v.y), pack2(v.z, v.w)};
    }
}

// ---------------------------------------------------------------------------
// Phase 1 (MFMA GEMM, ~40 us -- unchanged):
// pre[r][j] = b_i2h[j] + sum_i x[r][i]*Wx[i][j], f16 out.
// ---------------------------------------------------------------------------
__global__ __launch_bounds__(256) __attribute__((amdgpu_waves_per_eu(2, 2)))
void k_phase1(const float* __restrict__ seq, const uint4* __restrict__ wxb4,
              const float* __restrict__ bias, u16* __restrict__ pre) {
    int w = threadIdx.x >> 6, l = threadIdx.x & 63;
    int lm = l & 15, lq = l >> 4;
    int mb_w = blockIdx.x * 64 + w * 16;
    long xrow = (long)(mb_w + lm) * I_;
#define DECLA1(k) uint4 a##k; { \
        const float4* xp = (const float4*)(seq + xrow + (k)*32 + lq*8); \
        float4 u = xp[0], v = xp[1]; \
        a##k = (uint4){pack2(u.x,u.y), pack2(u.z,u.w), pack2(v.x,v.y), pack2(v.z,v.w)}; }
    REP8(DECLA1)
#undef DECLA1
    int mrow0 = mb_w + lq * 4;
#pragma unroll
    for (int half = 0; half < 2; ++half) {
        int colbase = half * 256;
        const uint4* bptr = wxb4 + colbase + lm;
#define DECLC(n) float bv##n = bias[colbase + (n)*16 + lm]; \
                 f32x4 c##n = {bv##n, bv##n, bv##n, bv##n};
        REP16(DECLC)
#undef DECLC
#define ROW(k,n) c##n = mf(a##k, bptr + ((k)*4 + lq)*512 + (n)*16, c##n);
#define KS(k) ROW(k,0) ROW(k,1) ROW(k,2) ROW(k,3) ROW(k,4) ROW(k,5) ROW(k,6) ROW(k,7) \
              ROW(k,8) ROW(k,9) ROW(k,10) ROW(k,11) ROW(k,12) ROW(k,13) ROW(k,14) ROW(k,15)
        KS(0) KS(1) KS(2) KS(3) KS(4) KS(5) KS(6) KS(7)
#undef KS
#undef ROW
#define STN(n) { long cb = (long)colbase + (n)*16 + lm; \
        pre[(long)(mrow0+0)*H_ + cb] = f2h(c##n[0]); \
        pre[(long)(mrow0+1)*H_ + cb] = f2h(c##n[1]); \
        pre[(long)(mrow0+2)*H_ + cb] = f2h(c##n[2]); \
        pre[(long)(mrow0+3)*H_ + cb] = f2h(c##n[3]); }
        REP16(STN)
#undef STN
    }
}

// ---------------------------------------------------------------------------
// Phase 2 v2: persistent split-K recurrence. One WG = one batch row,
// 1024 threads = 16 waves = 4 waves/SIMD (was 2 -- latency-hiding fix).
// Thread t: column j = t&511, K-half kh = t>>9. Each thread owns 32 slabs
// (= 256 of the 512 h-terms of its column):
//   offs  0..12 resident VGPR | 13..15 LDS | 16..31 streamed from L2.
// h broadcast: lanes 0..31 of each wave hold the K-half's 128 h-pairs
// (uint4 = 4 pairs each); pair 4*o+c of the half comes from lane o via
// v_readlane (o = slab offset 0..31). Partials exchanged via pbuf (f32 LDS),
// kh==0 finalizes tanh. Two barriers per step.
// VGPR plan: 52 w + <=32 stream-in-flight + 12 LDS-tmp + hv4 + acc4 + misc
// ~ 110 < 128 (4 waves/EU budget).
// ---------------------------------------------------------------------------
__global__ __launch_bounds__(1024) __attribute__((amdgpu_waves_per_eu(4, 4)))
void k_phase2(const u16* __restrict__ pre, const uint4* __restrict__ whb4,
              const float* __restrict__ Who, const float* __restrict__ bo,
              float* __restrict__ out) {
    __shared__ __align__(16) uint4 wlds[3 * 1024];  // 48 KB, slab offs 13..15
    __shared__ __align__(16) u16 hbuf[2][H_];
    __shared__ float pbuf[H_];                      // kh==1 partial sums
    int b = blockIdx.x, t_ = threadIdx.x;
    int j = t_ & 511, kh = t_ >> 9, lane = t_ & 63;
    int q0 = kh << 5;                               // slab window base (0 / 32)
#define DECLW(i) uint4 w##i = whb4[(q0 + (i)) * 512 + j];
    RESOFFS(DECLW)
#undef DECLW
#pragma unroll
    for (int s_ = 0; s_ < 3; ++s_) wlds[s_ * 1024 + t_] = whb4[(q0 + 13 + s_) * 512 + j];
    const u16* prow = pre + (long)b * S_ * H_ + j;
    ((u16*)hbuf)[t_] = 0;                           // zero both h buffers
    __syncthreads();
    u16 pv = 0;
    if (!kh) pv = prow[0];                          // pre for t=0 (kh0 only)
    int hvi = (kh << 8) + ((lane & 31) << 3);       // u16 idx of this lane's 4 pairs
    for (int t = 0; t < S_; ++t) {
        int cur = t & 1, nxt = cur ^ 1;
        long tn = (t + 1 < S_) ? (long)(t + 1) : (long)t;
        int zoff = 0, lz = 0;
        asm volatile("" : "+v"(zoff), "+v"(lz));    // block LICM of weight loads
        u16 pnext = 0;
        if (!kh) pnext = prow[tn * H_];             // prefetch next step's pre
        uint4 hv = *(const uint4*)(&hbuf[cur][hvi]);
        float a0 = kh ? 0.f : h2f_(pv), a1 = 0.f, a2 = 0.f, a3 = 0.f;
#define SLOAD(o) uint4 s##o = whb4[(q0 + (o)) * 512 + j + zoff];
#define SDOT(o) \
        a0 = fdot2u((u32)__builtin_amdgcn_readlane((int)hv.x, (o)), s##o.x, a0); \
        a1 = fdot2u((u32)__builtin_amdgcn_readlane((int)hv.y, (o)), s##o.y, a1); \
        a2 = fdot2u((u32)__builtin_amdgcn_readlane((int)hv.z, (o)), s##o.z, a2); \
        a3 = fdot2u((u32)__builtin_amdgcn_readlane((int)hv.w, (o)), s##o.w, a3);
#define DOTR(i) \
        a0 = fdot2u((u32)__builtin_amdgcn_readlane((int)hv.x, (i)), w##i.x, a0); \
        a1 = fdot2u((u32)__builtin_amdgcn_readlane((int)hv.y, (i)), w##i.y, a1); \
        a2 = fdot2u((u32)__builtin_amdgcn_readlane((int)hv.z, (i)), w##i.z, a2); \
        a3 = fdot2u((u32)__builtin_amdgcn_readlane((int)hv.w, (i)), w##i.w, a3);
#define LLOAD(i) uint4 t##i = wlds[(i) * 1024 + t_ + lz];
#define LDOT(i) \
        a0 = fdot2u((u32)__builtin_amdgcn_readlane((int)hv.x, 13 + (i)), t##i.x, a0); \
        a1 = fdot2u((u32)__builtin_amdgcn_readlane((int)hv.y, 13 + (i)), t##i.y, a1); \
        a2 = fdot2u((u32)__builtin_amdgcn_readlane((int)hv.z, 13 + (i)), t##i.z, a2); \
        a3 = fdot2u((u32)__builtin_amdgcn_readlane((int)hv.w, 13 + (i)), t##i.w, a3);
        CH_A(SLOAD)                                 // 4 loads in flight
        RES_A(DOTR)                                 // 6 resident slabs (covers A)
        CH_B(SLOAD)                                 // 4 more in flight
        RES_B(DOTR)                                 // 7 resident slabs (covers B)
        CH_A(SDOT)
        CH_C(SLOAD)
        __builtin_amdgcn_sched_barrier(0);          // keep back half below
        CH_B(SDOT)
        CH_D(SLOAD)
        LDS3(LLOAD)                                 // 3 LDS slabs in flight
        CH_C(SDOT)
        LDS3(LDOT)
        CH_D(SDOT)
#undef SLOAD
#undef SDOT
#undef DOTR
#undef LLOAD
#undef LDOT
        float acc = (a0 + a1) + (a2 + a3);
        if (kh) pbuf[j] = acc;                      // publish upper-half partial
        __syncthreads();                            // partials visible
        if (!kh) hbuf[nxt][j] = f2h(tanh_fast(acc + pbuf[j]));
        pv = pnext;
        __syncthreads();                            // h_{t} visible to all
    }
    // final h lives in hbuf[0] (last write: t=1023 -> nxt=0)
    if (!kh) {
        float hj = h2f_(hbuf[0][j]);
        out[(long)B_ * O_ + (long)b * H_ + j] = hj; // hidden output
    }
    if (t_ < O_) {                                  // o = h @ W_h2o^T + b_h2o
        float acc = bo[t_];
        const float4* wr = (const float4*)(Who + (long)t_ * H_);
        const u16* hb = hbuf[0];
#pragma unroll 4
        for (int k = 0; k < 128; ++k) {
            float4 wv = wr[k];
            acc += h2f_(hb[4 * k + 0]) * wv.x
                 + h2f_(hb[4 * k + 1]) * wv.y
                 + h2f_(hb[4 * k + 2]) * wv.z
                 + h2f_(hb[4 * k + 3]) * wv.w;
        }
        out[(long)b * O_ + t_] = acc;
    }
}

// ---------------------------------------------------------------------------
// Fallback (workspace too small): straightforward fp32, correct but slow.
// ---------------------------------------------------------------------------
__global__ __launch_bounds__(512) void k_fallback(const float* __restrict__ seq,
                                                  const float* __restrict__ W,
                                                  const float* __restrict__ bias,
                                                  const float* __restrict__ Who,
                                                  const float* __restrict__ bo,
                                                  float* __restrict__ out) {
    __shared__ float hb[2][H_];
    int b = blockIdx.x, j = threadIdx.x;
    const float* wrow = W + (long)j * IH_;
    float bj = bias[j];
    hb[0][j] = 0.f;
    __syncthreads();
    for (int t = 0; t < S_; ++t) {
        const float* x = seq + ((long)b * S_ + t) * I_;
        float acc = bj;
        for (int i = 0; i < I_; ++i) acc += x[i] * wrow[i];
        const float* hc = hb[t & 1];
        for (int k = 0; k < H_; ++k) acc += hc[k] * wrow[I_ + k];
        hb[(t & 1) ^ 1][j] = tanh_fast(acc);
        __syncthreads();
    }
    float hj = hb[0][j];
    out[(long)B_ * O_ + (long)b * H_ + j] = hj;
    if (j < O_) {
        float acc = bo[j];
        const float* wr = Who + (long)j * H_;
        for (int k = 0; k < H_; ++k) acc += hb[0][k] * wr[k];
        out[(long)b * O_ + j] = acc;
    }
}

extern "C" void kernel_launch(void* const* d_in, const int* in_sizes, int n_in,
                              void* d_out, int out_size, void* d_ws, size_t ws_size,
                              hipStream_t stream) {
    const float* seq = (const float*)d_in[0];   // (128,1024,256) fp32
    const float* W   = (const float*)d_in[1];   // (512,768) fp32
    const float* bi  = (const float*)d_in[2];   // (512,)
    const float* Who = (const float*)d_in[3];   // (256,512)
    const float* bo  = (const float*)d_in[4];   // (256,)
    float* out = (float*)d_out;                 // 32768 output + 65536 hidden

    const size_t WS_NEED = (size_t)PRE_OFF + (size_t)B_ * S_ * H_ * 2;

    if (ws_size >= WS_NEED) {
        char* ws = (char*)d_ws;
        uint4* wxb4 = (uint4*)(ws + WXB_OFF);
        uint4* whb4 = (uint4*)(ws + WHB_OFF);
        u16*   pre  = (u16*)(ws + PRE_OFF);
        k_convert<<<192, 256, 0, stream>>>(W, wxb4, whb4);
        k_phase1<<<2048, 256, 0, stream>>>(seq, wxb4, bi, pre);
        k_phase2<<<B_, 1024, 0, stream>>>(pre, whb4, Who, bo, out);
    } else {
        k_fallback<<<B_, 512, 0, stream>>>(seq, W, bi, Who, bo, out);
    }
}

// Round 2
// 2641.973 us; speedup vs baseline: 1.2761x; 1.2761x over previous
//
#include <hip/hip_runtime.h>

typedef _Float16 h2f __attribute__((ext_vector_type(2)));
typedef _Float16 f16x8 __attribute__((ext_vector_type(8)));
typedef float f32x4 __attribute__((ext_vector_type(4)));
typedef unsigned int u32;
typedef unsigned short u16;

#define B_ 128
#define S_ 1024
#define I_ 256
#define H_ 512
#define O_ 256
#define IH_ 768

#if __has_builtin(__builtin_amdgcn_fdot2)
__device__ __forceinline__ float fdot2u(u32 a, u32 b, float c) {
    return __builtin_amdgcn_fdot2(__builtin_bit_cast(h2f, a),
                                  __builtin_bit_cast(h2f, b), c, false);
}
#else
__device__ __forceinline__ float fdot2u(u32 a, u32 b, float c) {
    h2f av = __builtin_bit_cast(h2f, a), bv = __builtin_bit_cast(h2f, b);
    return c + (float)av.x * (float)bv.x + (float)av.y * (float)bv.y;
}
#endif

__device__ __forceinline__ u32 pack2(float x, float y) {
    return __builtin_bit_cast(u32, __builtin_amdgcn_cvt_pkrtz(x, y));
}
__device__ __forceinline__ u16 f2h(float x) { return __builtin_bit_cast(u16, (_Float16)x); }
__device__ __forceinline__ float h2f_(u16 x) { return (float)__builtin_bit_cast(_Float16, x); }

__device__ __forceinline__ float tanh_fast(float x) {
    float e = __expf(-2.f * fabsf(x));     // e in (0,1] -- no overflow path
    float r = (1.f - e) / (1.f + e);
    return copysignf(r, x);
}

// MFMA helper (phase 1): D = A(16x32)*B(32x16)+C, f16 in / f32 acc.
// Verified layouts (m89/m91): A[m=lane&15][k=(lane>>4)*8+j],
// B[k=(lane>>4)*8+j][n=lane&15], C/D col=lane&15 row=(lane>>4)*4+reg.
__device__ __forceinline__ f32x4 mfx(uint4 a, uint4 b, f32x4 c) {
    return __builtin_amdgcn_mfma_f32_16x16x32_f16(
        __builtin_bit_cast(f16x8, a), __builtin_bit_cast(f16x8, b), c, 0, 0, 0);
}
__device__ __forceinline__ f32x4 mf(uint4 a, const uint4* bp, f32x4 c) {
    uint4 b = *bp;
    return mfx(a, b, c);
}

#define REP8(X)  X(0) X(1) X(2) X(3) X(4) X(5) X(6) X(7)
#define REP16(X) REP8(X) X(8) X(9) X(10) X(11) X(12) X(13) X(14) X(15)

// phase-2 slab partition (64 slabs per hidden column, 16 B each):
//   offs  0..41 : 42 NAMED uint4 resident in VGPRs/AGPRs (v1-proven budget)
//   offs 42..57 : 16 slabs LDS-resident (128 KB static, filled once)
//                 -- was 6 in v1; the 16 L2-streamed slabs were the stall
//                 (128 KB/step/CU through L1 at ~64 B/cyc ~ 2000 cyc/step)
//   offs 58..63 : 6 slabs streamed from L2 per step (48 KB/step ~ 750 cyc)
#define REPW_A(X) X(0) X(1) X(2) X(3) X(4) X(5) X(6) X(7) X(8) X(9) X(10) \
                  X(11) X(12) X(13) X(14) X(15) X(16) X(17) X(18) X(19) X(20)
#define REPW_B(X) X(21) X(22) X(23) X(24) X(25) X(26) X(27) X(28) X(29) X(30) \
                  X(31) X(32) X(33) X(34) X(35) X(36) X(37) X(38) X(39) X(40) X(41)
#define REP42(X) REPW_A(X) REPW_B(X)
#define LDS_A(X) X(0) X(1) X(2) X(3)
#define LDS_B(X) X(4) X(5) X(6) X(7)
#define LDS_C(X) X(8) X(9) X(10) X(11)
#define LDS_D(X) X(12) X(13) X(14) X(15)
#define STR6(X) X(0) X(1) X(2) X(3) X(4) X(5)

// ---------------------------------------------------------------------------
// Workspace layout (bytes):
//   wxb4 @ 0      : 16384 uint4 (256 KB)  Wx octets [q 0..31][col 0..511]
//                   octet q of col c = W[c][q*8 .. q*8+7] as f16
//   whb4 @ 256 KB : 32768 uint4 (512 KB)  Wh octets [q 0..63][n 0..511]
//                   octet q of col n = W[n][256+q*8 .. +7] as f16
//   pre  @ 1 MB   : 128*1024*512 f16 (128 MB)
// ---------------------------------------------------------------------------
#define WXB_OFF 0
#define WHB_OFF (256u << 10)
#define PRE_OFF (1u << 20)

__global__ __launch_bounds__(256) void k_convert(const float* __restrict__ W,
                                                 uint4* __restrict__ wxb4,
                                                 uint4* __restrict__ whb4) {
    int idx = blockIdx.x * 256 + threadIdx.x;       // 0..49151
    if (idx < 16384) {                               // wxb: q = idx>>9 (0..31)
        int q = idx >> 9, col = idx & 511;
        const float4* r = (const float4*)(W + (long)col * IH_ + q * 8);
        float4 u = r[0], v = r[1];
        wxb4[idx] = (uint4){pack2(u.x, u.y), pack2(u.z, u.w),
                            pack2(v.x, v.y), pack2(v.z, v.w)};
    } else {                                         // whb: q = 0..63
        int i2 = idx - 16384;
        int q = i2 >> 9, n = i2 & 511;
        const float4* r = (const float4*)(W + (long)n * IH_ + I_ + q * 8);
        float4 u = r[0], v = r[1];
        whb4[i2] = (uint4){pack2(u.x, u.y), pack2(u.z, u.w),
                           pack2(v.x, v.y), pack2(v.z, v.w)};
    }
}

// ---------------------------------------------------------------------------
// Phase 1 (MFMA GEMM, ~40 us -- unchanged):
// pre[r][j] = b_i2h[j] + sum_i x[r][i]*Wx[i][j], f16 out.
// ---------------------------------------------------------------------------
__global__ __launch_bounds__(256) __attribute__((amdgpu_waves_per_eu(2, 2)))
void k_phase1(const float* __restrict__ seq, const uint4* __restrict__ wxb4,
              const float* __restrict__ bias, u16* __restrict__ pre) {
    int w = threadIdx.x >> 6, l = threadIdx.x & 63;
    int lm = l & 15, lq = l >> 4;
    int mb_w = blockIdx.x * 64 + w * 16;
    long xrow = (long)(mb_w + lm) * I_;
#define DECLA1(k) uint4 a##k; { \
        const float4* xp = (const float4*)(seq + xrow + (k)*32 + lq*8); \
        float4 u = xp[0], v = xp[1]; \
        a##k = (uint4){pack2(u.x,u.y), pack2(u.z,u.w), pack2(v.x,v.y), pack2(v.z,v.w)}; }
    REP8(DECLA1)
#undef DECLA1
    int mrow0 = mb_w + lq * 4;
#pragma unroll
    for (int half = 0; half < 2; ++half) {
        int colbase = half * 256;
        const uint4* bptr = wxb4 + colbase + lm;
#define DECLC(n) float bv##n = bias[colbase + (n)*16 + lm]; \
                 f32x4 c##n = {bv##n, bv##n, bv##n, bv##n};
        REP16(DECLC)
#undef DECLC
#define ROW(k,n) c##n = mf(a##k, bptr + ((k)*4 + lq)*512 + (n)*16, c##n);
#define KS(k) ROW(k,0) ROW(k,1) ROW(k,2) ROW(k,3) ROW(k,4) ROW(k,5) ROW(k,6) ROW(k,7) \
              ROW(k,8) ROW(k,9) ROW(k,10) ROW(k,11) ROW(k,12) ROW(k,13) ROW(k,14) ROW(k,15)
        KS(0) KS(1) KS(2) KS(3) KS(4) KS(5) KS(6) KS(7)
#undef KS
#undef ROW
#define STN(n) { long cb = (long)colbase + (n)*16 + lm; \
        pre[(long)(mrow0+0)*H_ + cb] = f2h(c##n[0]); \
        pre[(long)(mrow0+1)*H_ + cb] = f2h(c##n[1]); \
        pre[(long)(mrow0+2)*H_ + cb] = f2h(c##n[2]); \
        pre[(long)(mrow0+3)*H_ + cb] = f2h(c##n[3]); }
        REP16(STN)
#undef STN
    }
}

// ---------------------------------------------------------------------------
// Phase 2 v3: v1 structure (512 thr, one barrier/step) with the L2 weight
// stream moved into LDS. Slab schedule per thread (column j):
//   0..41 VGPR-resident | 42..57 LDS-resident (128 KB) | 58..63 L2-streamed.
// h ping-pong in LDS f16; lane l reads h pairs 4l..4l+3 (one ds_read_b128),
// pair 4q+c broadcast from lane q via v_readlane. One barrier per step.
// zoff/lz asm-barriers block LICM (hoisting 64 uint4 = the spill trigger).
// ---------------------------------------------------------------------------
__global__ __launch_bounds__(512) __attribute__((amdgpu_waves_per_eu(2, 2)))
void k_phase2(const u16* __restrict__ pre, const uint4* __restrict__ whb4,
              const float* __restrict__ Who, const float* __restrict__ bo,
              float* __restrict__ out) {
    __shared__ __align__(16) uint4 wlds[16 * 512];  // 128 KB, slabs q=42..57
    __shared__ __align__(16) u16 hbuf[2][H_];
    int b = blockIdx.x, j = threadIdx.x, lane = j & 63;
#define DECLW(i) uint4 w##i = whb4[(i) * 512 + j];
    REP42(DECLW)
#undef DECLW
#pragma unroll
    for (int s_ = 0; s_ < 16; ++s_) wlds[s_ * 512 + j] = whb4[(42 + s_) * 512 + j];
    const u16* prow = pre + (long)b * S_ * H_ + j;
    hbuf[0][j] = 0;                                 // h_{-1} = 0
    __syncthreads();
    u16 pv = prow[0];                               // pre for t=0
    for (int t = 0; t < S_; ++t) {
        int cur = t & 1, nxt = cur ^ 1;
        long tn = (t + 1 < S_) ? (long)(t + 1) : (long)t;
        int zoff = 0, lz = 0;
        asm volatile("" : "+v"(zoff), "+v"(lz));    // block LICM of weight loads
        u16 pnext = prow[tn * H_];                  // prefetch next step's pre
        uint4 hv = ((const uint4*)hbuf[cur])[lane]; // lane l: h pairs 4l..4l+3
        float a0 = h2f_(pv), a1 = 0.f, a2 = 0.f, a3 = 0.f;
#define SLOAD(o) uint4 s##o = whb4[(58 + (o)) * 512 + j + zoff];
#define SDOT(o) \
        a0 = fdot2u((u32)__builtin_amdgcn_readlane((int)hv.x, 58 + (o)), s##o.x, a0); \
        a1 = fdot2u((u32)__builtin_amdgcn_readlane((int)hv.y, 58 + (o)), s##o.y, a1); \
        a2 = fdot2u((u32)__builtin_amdgcn_readlane((int)hv.z, 58 + (o)), s##o.z, a2); \
        a3 = fdot2u((u32)__builtin_amdgcn_readlane((int)hv.w, 58 + (o)), s##o.w, a3);
#define DOTR(i) \
        a0 = fdot2u((u32)__builtin_amdgcn_readlane((int)hv.x, (i)), w##i.x, a0); \
        a1 = fdot2u((u32)__builtin_amdgcn_readlane((int)hv.y, (i)), w##i.y, a1); \
        a2 = fdot2u((u32)__builtin_amdgcn_readlane((int)hv.z, (i)), w##i.z, a2); \
        a3 = fdot2u((u32)__builtin_amdgcn_readlane((int)hv.w, (i)), w##i.w, a3);
#define LLOAD(i) uint4 t##i = wlds[(i) * 512 + j + lz];
#define LDOT(i) \
        a0 = fdot2u((u32)__builtin_amdgcn_readlane((int)hv.x, 42 + (i)), t##i.x, a0); \
        a1 = fdot2u((u32)__builtin_amdgcn_readlane((int)hv.y, 42 + (i)), t##i.y, a1); \
        a2 = fdot2u((u32)__builtin_amdgcn_readlane((int)hv.z, 42 + (i)), t##i.z, a2); \
        a3 = fdot2u((u32)__builtin_amdgcn_readlane((int)hv.w, 42 + (i)), t##i.w, a3);
        STR6(SLOAD)                                 // 6 L2 loads in flight
        LDS_A(LLOAD)                                // 4 LDS reads in flight
        REPW_A(DOTR)                                // 21 resident slabs
        LDS_A(LDOT)
        LDS_B(LLOAD)
        __builtin_amdgcn_sched_barrier(0);          // pin chunk structure
        REPW_B(DOTR)                                // 21 resident slabs
        LDS_B(LDOT)
        LDS_C(LLOAD)
        __builtin_amdgcn_sched_barrier(0);
        LDS_C(LDOT)
        LDS_D(LLOAD)
        LDS_D(LDOT)
        STR6(SDOT)                                  // streamed slabs last
#undef SLOAD
#undef SDOT
#undef DOTR
#undef LLOAD
#undef LDOT
        float acc = (a0 + a1) + (a2 + a3);
        float r = tanh_fast(acc);
        hbuf[nxt][j] = f2h(r);
        pv = pnext;
        __syncthreads();
    }
    // final h lives in hbuf[0] (last write: t=1023 -> nxt=0)
    float hj = h2f_(hbuf[0][j]);
    out[(long)B_ * O_ + (long)b * H_ + j] = hj;     // hidden output
    if (j < O_) {                                   // o = h @ W_h2o^T + b_h2o
        float acc = bo[j];
        const float4* wr = (const float4*)(Who + (long)j * H_);
        const u16* hb = hbuf[0];
#pragma unroll 4
        for (int k = 0; k < 128; ++k) {
            float4 wv = wr[k];
            acc += h2f_(hb[4 * k + 0]) * wv.x
                 + h2f_(hb[4 * k + 1]) * wv.y
                 + h2f_(hb[4 * k + 2]) * wv.z
                 + h2f_(hb[4 * k + 3]) * wv.w;
        }
        out[(long)b * O_ + j] = acc;
    }
}

// ---------------------------------------------------------------------------
// Fallback (workspace too small): straightforward fp32, correct but slow.
// ---------------------------------------------------------------------------
__global__ __launch_bounds__(512) void k_fallback(const float* __restrict__ seq,
                                                  const float* __restrict__ W,
                                                  const float* __restrict__ bias,
                                                  const float* __restrict__ Who,
                                                  const float* __restrict__ bo,
                                                  float* __restrict__ out) {
    __shared__ float hb[2][H_];
    int b = blockIdx.x, j = threadIdx.x;
    const float* wrow = W + (long)j * IH_;
    float bj = bias[j];
    hb[0][j] = 0.f;
    __syncthreads();
    for (int t = 0; t < S_; ++t) {
        const float* x = seq + ((long)b * S_ + t) * I_;
        float acc = bj;
        for (int i = 0; i < I_; ++i) acc += x[i] * wrow[i];
        const float* hc = hb[t & 1];
        for (int k = 0; k < H_; ++k) acc += hc[k] * wrow[I_ + k];
        hb[(t & 1) ^ 1][j] = tanh_fast(acc);
        __syncthreads();
    }
    float hj = hb[0][j];
    out[(long)B_ * O_ + (long)b * H_ + j] = hj;
    if (j < O_) {
        float acc = bo[j];
        const float* wr = Who + (long)j * H_;
        for (int k = 0; k < H_; ++k) acc += hb[0][k] * wr[k];
        out[(long)b * O_ + j] = acc;
    }
}

extern "C" void kernel_launch(void* const* d_in, const int* in_sizes, int n_in,
                              void* d_out, int out_size, void* d_ws, size_t ws_size,
                              hipStream_t stream) {
    const float* seq = (const float*)d_in[0];   // (128,1024,256) fp32
    const float* W   = (const float*)d_in[1];   // (512,768) fp32
    const float* bi  = (const float*)d_in[2];   // (512,)
    const float* Who = (const float*)d_in[3];   // (256,512)
    const float* bo  = (const float*)d_in[4];   // (256,)
    float* out = (float*)d_out;                 // 32768 output + 65536 hidden

    const size_t WS_NEED = (size_t)PRE_OFF + (size_t)B_ * S_ * H_ * 2;

    if (ws_size >= WS_NEED) {
        char* ws = (char*)d_ws;
        uint4* wxb4 = (uint4*)(ws + WXB_OFF);
        uint4* whb4 = (uint4*)(ws + WHB_OFF);
        u16*   pre  = (u16*)(ws + PRE_OFF);
        k_convert<<<192, 256, 0, stream>>>(W, wxb4, whb4);
        k_phase1<<<2048, 256, 0, stream>>>(seq, wxb4, bi, pre);
        k_phase2<<<B_, 512, 0, stream>>>(pre, whb4, Who, bo, out);
    } else {
        k_fallback<<<B_, 512, 0, stream>>>(seq, W, bi, Who, bo, out);
    }
}

// Round 4
// 1941.304 us; speedup vs baseline: 1.7366x; 1.3609x over previous
//
#include <hip/hip_runtime.h>

typedef _Float16 h2f __attribute__((ext_vector_type(2)));
typedef _Float16 f16x8 __attribute__((ext_vector_type(8)));
typedef float f32x4 __attribute__((ext_vector_type(4)));
typedef unsigned int u32;
typedef unsigned short u16;

#define B_ 128
#define S_ 1024
#define I_ 256
#define H_ 512
#define O_ 256
#define IH_ 768

#if __has_builtin(__builtin_amdgcn_fdot2)
__device__ __forceinline__ float fdot2u(u32 a, u32 b, float c) {
    return __builtin_amdgcn_fdot2(__builtin_bit_cast(h2f, a),
                                  __builtin_bit_cast(h2f, b), c, false);
}
#else
__device__ __forceinline__ float fdot2u(u32 a, u32 b, float c) {
    h2f av = __builtin_bit_cast(h2f, a), bv = __builtin_bit_cast(h2f, b);
    return c + (float)av.x * (float)bv.x + (float)av.y * (float)bv.y;
}
#endif

__device__ __forceinline__ u32 pack2(float x, float y) {
    return __builtin_bit_cast(u32, __builtin_amdgcn_cvt_pkrtz(x, y));
}
__device__ __forceinline__ u16 f2h(float x) { return __builtin_bit_cast(u16, (_Float16)x); }
__device__ __forceinline__ float h2f_(u16 x) { return (float)__builtin_bit_cast(_Float16, x); }

__device__ __forceinline__ float tanh_fast(float x) {
    float e = __expf(-2.f * fabsf(x));     // e in (0,1] -- no overflow path
    float r = (1.f - e) / (1.f + e);
    return copysignf(r, x);
}

// MFMA: D = A(16x32)*B(32x16)+C, f16 in / f32 acc.
// Verified layouts (m89/m91): A[m=lane&15][k=(lane>>4)*8+j],
// B[k=(lane>>4)*8+j][n=lane&15], C/D col=lane&15 row=(lane>>4)*4+reg.
__device__ __forceinline__ f32x4 mfx(uint4 a, uint4 b, f32x4 c) {
    return __builtin_amdgcn_mfma_f32_16x16x32_f16(
        __builtin_bit_cast(f16x8, a), __builtin_bit_cast(f16x8, b), c, 0, 0, 0);
}
__device__ __forceinline__ f32x4 mf(uint4 a, const uint4* bp, f32x4 c) {
    uint4 b = *bp;
    return mfx(a, b, c);
}

#define REP8(X)  X(0) X(1) X(2) X(3) X(4) X(5) X(6) X(7)
#define REP16(X) REP8(X) X(8) X(9) X(10) X(11) X(12) X(13) X(14) X(15)
#define REPK10(X) X(0) X(1) X(2) X(3) X(4) X(5) X(6) X(7) X(8) X(9)

// ---------------------------------------------------------------------------
// Workspace layout (bytes):
//   wxb4 @ 0      : 16384 uint4 (256 KB)  Wx octets [q 0..31][col 0..511]
//                   octet q of col c = W[c][q*8 .. q*8+7] as f16
//   whb4 @ 256 KB : 32768 uint4 (512 KB)  Wh octets [q 0..63][n 0..511]
//                   octet q of col n = W[n][256+q*8 .. +7] as f16
//   pre  @ 1 MB   : 128*1024*512 f16 (128 MB)
// ---------------------------------------------------------------------------
#define WXB_OFF 0
#define WHB_OFF (256u << 10)
#define PRE_OFF (1u << 20)

__global__ __launch_bounds__(256) void k_convert(const float* __restrict__ W,
                                                 uint4* __restrict__ wxb4,
                                                 uint4* __restrict__ whb4) {
    int idx = blockIdx.x * 256 + threadIdx.x;       // 0..49151
    if (idx < 16384) {                               // wxb: q = idx>>9 (0..31)
        int q = idx >> 9, col = idx & 511;
        const float4* r = (const float4*)(W + (long)col * IH_ + q * 8);
        float4 u = r[0], v = r[1];
        wxb4[idx] = (uint4){pack2(u.x, u.y), pack2(u.z, u.w),
                            pack2(v.x, v.y), pack2(v.z, v.w)};
    } else {                                         // whb: q = 0..63
        int i2 = idx - 16384;
        int q = i2 >> 9, n = i2 & 511;
        const float4* r = (const float4*)(W + (long)n * IH_ + I_ + q * 8);
        float4 u = r[0], v = r[1];
        whb4[i2] = (uint4){pack2(u.x, u.y), pack2(u.z, u.w),
                           pack2(v.x, v.y), pack2(v.z, v.w)};
    }
}

// ---------------------------------------------------------------------------
// Phase 1 (MFMA GEMM, ~40 us -- unchanged):
// pre[r][j] = b_i2h[j] + sum_i x[r][i]*Wx[i][j], f16 out.
// ---------------------------------------------------------------------------
__global__ __launch_bounds__(256) __attribute__((amdgpu_waves_per_eu(2, 2)))
void k_phase1(const float* __restrict__ seq, const uint4* __restrict__ wxb4,
              const float* __restrict__ bias, u16* __restrict__ pre) {
    int w = threadIdx.x >> 6, l = threadIdx.x & 63;
    int lm = l & 15, lq = l >> 4;
    int mb_w = blockIdx.x * 64 + w * 16;
    long xrow = (long)(mb_w + lm) * I_;
#define DECLA1(k) uint4 a##k; { \
        const float4* xp = (const float4*)(seq + xrow + (k)*32 + lq*8); \
        float4 u = xp[0], v = xp[1]; \
        a##k = (uint4){pack2(u.x,u.y), pack2(u.z,u.w), pack2(v.x,v.y), pack2(v.z,v.w)}; }
    REP8(DECLA1)
#undef DECLA1
    int mrow0 = mb_w + lq * 4;
#pragma unroll
    for (int half = 0; half < 2; ++half) {
        int colbase = half * 256;
        const uint4* bptr = wxb4 + colbase + lm;
#define DECLC(n) float bv##n = bias[colbase + (n)*16 + lm]; \
                 f32x4 c##n = {bv##n, bv##n, bv##n, bv##n};
        REP16(DECLC)
#undef DECLC
#define ROW(k,n) c##n = mf(a##k, bptr + ((k)*4 + lq)*512 + (n)*16, c##n);
#define KS(k) ROW(k,0) ROW(k,1) ROW(k,2) ROW(k,3) ROW(k,4) ROW(k,5) ROW(k,6) ROW(k,7) \
              ROW(k,8) ROW(k,9) ROW(k,10) ROW(k,11) ROW(k,12) ROW(k,13) ROW(k,14) ROW(k,15)
        KS(0) KS(1) KS(2) KS(3) KS(4) KS(5) KS(6) KS(7)
#undef KS
#undef ROW
#define STN(n) { long cb = (long)colbase + (n)*16 + lm; \
        pre[(long)(mrow0+0)*H_ + cb] = f2h(c##n[0]); \
        pre[(long)(mrow0+1)*H_ + cb] = f2h(c##n[1]); \
        pre[(long)(mrow0+2)*H_ + cb] = f2h(c##n[2]); \
        pre[(long)(mrow0+3)*H_ + cb] = f2h(c##n[3]); }
        REP16(STN)
#undef STN
    }
}

// ---------------------------------------------------------------------------
// Phase 2 v4 (resubmit -- R3 was an infra failure, source re-audited):
// MFMA recurrence via broadcast-A.
// One WG (512 thr = 8 waves) per batch row. Wave w owns cols 64w..64w+63
// as 4 col-groups g (16 cols each). Per step, per col-group:
//   acc_g = C-init(pre) ; for K=0..15: acc_g = mfma(A_K, B_{K,g}, acc_g)
// where A_K[m][k] = h[32K+k] for ALL m (broadcast rows -> result rows all
// equal = the full 512-term dot per column).
// B-fragment lane mapping == whb4 slab layout: lane reads
// whb4[4K+(lane>>4)][16N+(lane&15)] (one uint4 = 8 f16 of k).
// Fragment residency (per wave, 64 frags):
//   K 0..9  : 40 resident uint4 (160 VGPRs)
//   K 10..13: LDS (slabs 40..55, 128 KB static, filled once)
//   K 14..15: streamed from L2 each step (8 frags, 64 KB/step/WG)
// A_K read: ds_read_b128 at hbuf+64K+16*(lane>>4) -- 16-lane-uniform
// broadcast, conflict-free. h write-back: lane l writes col 64w+l via
// cndmask-select of acc_{l>>4}[0] (all rows/regs equal). One barrier/step.
// Replaces 2048 readlane+2048 fdot2 wave-instrs/CU/step with 512 MFMAs.
// ---------------------------------------------------------------------------
__global__ __launch_bounds__(512) __attribute__((amdgpu_waves_per_eu(2, 2)))
void k_phase2(const u16* __restrict__ pre, const uint4* __restrict__ whb4,
              const float* __restrict__ Who, const float* __restrict__ bo,
              float* __restrict__ out) {
    __shared__ __align__(16) uint4 wlds[16 * 512];  // 128 KB, slabs q=40..55
    __shared__ __align__(16) u16 hbuf[2][H_];
    int b = blockIdx.x, j = threadIdx.x;
    int w = j >> 6, lane = j & 63;
    int n_ = lane & 15, gq = lane >> 4;             // col-in-group, k-subrow
    int colbase = w * 64;
    int cb0 = colbase, cb1 = colbase + 16, cb2 = colbase + 32, cb3 = colbase + 48;
    // resident B-fragments, K = 0..9 (40 x uint4)
#define DECLB(K) \
    uint4 b##K##_0 = whb4[(4*(K) + gq) * 512 + cb0 + n_]; \
    uint4 b##K##_1 = whb4[(4*(K) + gq) * 512 + cb1 + n_]; \
    uint4 b##K##_2 = whb4[(4*(K) + gq) * 512 + cb2 + n_]; \
    uint4 b##K##_3 = whb4[(4*(K) + gq) * 512 + cb3 + n_];
    REPK10(DECLB)
#undef DECLB
#pragma unroll
    for (int s_ = 0; s_ < 16; ++s_) wlds[s_ * 512 + j] = whb4[(40 + s_) * 512 + j];
    // pre pointers: thread needs cols cb{g} + n_ each step (C-init values)
    const u16* pr = pre + (long)b * S_ * H_ + colbase + n_;
    hbuf[0][j] = 0;                                 // h_{-1} = 0
    __syncthreads();
    u16 pv0 = pr[0], pv1 = pr[16], pv2 = pr[32], pv3 = pr[48];
    for (int t = 0; t < S_; ++t) {
        int cur = t & 1, nxt = cur ^ 1;
        long tn = (t + 1 < S_) ? (long)(t + 1) : (long)t;
        int zoff = 0, lz = 0;
        asm volatile("" : "+v"(zoff), "+v"(lz));    // block LICM of weight loads
        // streamed B-fragments, K = 14..15 (8 x global b128, long shadow)
#define SLOADK(K, P) \
        uint4 s##P##_0 = whb4[(4*(K) + gq) * 512 + cb0 + n_ + zoff]; \
        uint4 s##P##_1 = whb4[(4*(K) + gq) * 512 + cb1 + n_ + zoff]; \
        uint4 s##P##_2 = whb4[(4*(K) + gq) * 512 + cb2 + n_ + zoff]; \
        uint4 s##P##_3 = whb4[(4*(K) + gq) * 512 + cb3 + n_ + zoff];
        SLOADK(14, e)
        SLOADK(15, f)
#undef SLOADK
        u16 pn0 = pr[tn * H_ +  0];                 // prefetch next step's pre
        u16 pn1 = pr[tn * H_ + 16];
        u16 pn2 = pr[tn * H_ + 32];
        u16 pn3 = pr[tn * H_ + 48];
        const u16* hc = hbuf[cur];
        // A-fragments: A_K = h[32K .. 32K+31] broadcast; lane reads 16B at
        // 64K + 16*gq bytes (uniform per 16-lane group -> LDS broadcast)
#define DECLA(K) uint4 a##K = *(const uint4*)(hc + 32*(K) + 8*gq);
        // LDS B-fragments, K = 10..13
#define LB(K) \
        uint4 l##K##_0 = wlds[(4*((K)-10) + gq) * 512 + cb0 + n_ + lz]; \
        uint4 l##K##_1 = wlds[(4*((K)-10) + gq) * 512 + cb1 + n_ + lz]; \
        uint4 l##K##_2 = wlds[(4*((K)-10) + gq) * 512 + cb2 + n_ + lz]; \
        uint4 l##K##_3 = wlds[(4*((K)-10) + gq) * 512 + cb3 + n_ + lz];
#define MK4(K, B0, B1, B2, B3) \
        c0 = mfx(a##K, B0, c0); c1 = mfx(a##K, B1, c1); \
        c2 = mfx(a##K, B2, c2); c3 = mfx(a##K, B3, c3);
        float p0f = h2f_(pv0), p1f = h2f_(pv1), p2f = h2f_(pv2), p3f = h2f_(pv3);
        f32x4 c0 = {p0f, p0f, p0f, p0f};
        f32x4 c1 = {p1f, p1f, p1f, p1f};
        f32x4 c2 = {p2f, p2f, p2f, p2f};
        f32x4 c3 = {p3f, p3f, p3f, p3f};
        DECLA(0) DECLA(1) DECLA(2) DECLA(3)
        MK4(0, b0_0, b0_1, b0_2, b0_3)
        MK4(1, b1_0, b1_1, b1_2, b1_3)
        MK4(2, b2_0, b2_1, b2_2, b2_3)
        DECLA(4) DECLA(5) DECLA(6) DECLA(7)
        MK4(3, b3_0, b3_1, b3_2, b3_3)
        MK4(4, b4_0, b4_1, b4_2, b4_3)
        MK4(5, b5_0, b5_1, b5_2, b5_3)
        LB(10) LB(11)
        DECLA(8) DECLA(9) DECLA(10) DECLA(11)
        MK4(6, b6_0, b6_1, b6_2, b6_3)
        MK4(7, b7_0, b7_1, b7_2, b7_3)
        MK4(8, b8_0, b8_1, b8_2, b8_3)
        LB(12) LB(13)
        DECLA(12) DECLA(13) DECLA(14) DECLA(15)
        MK4(9, b9_0, b9_1, b9_2, b9_3)
        MK4(10, l10_0, l10_1, l10_2, l10_3)
        MK4(11, l11_0, l11_1, l11_2, l11_3)
        MK4(12, l12_0, l12_1, l12_2, l12_3)
        MK4(13, l13_0, l13_1, l13_2, l13_3)
        MK4(14, se_0, se_1, se_2, se_3)
        MK4(15, sf_0, sf_1, sf_2, sf_3)
#undef MK4
#undef LB
#undef DECLA
        // all 16 D-rows equal -> any reg holds the col value; lane l's output
        // col = colbase + l -> group l>>4, col-in-group l&15
        float v = c0[0];
        v = (gq == 1) ? c1[0] : v;
        v = (gq == 2) ? c2[0] : v;
        v = (gq == 3) ? c3[0] : v;
        hbuf[nxt][colbase + lane] = f2h(tanh_fast(v));
        pv0 = pn0; pv1 = pn1; pv2 = pn2; pv3 = pn3;
        __syncthreads();
    }
    // final h lives in hbuf[0] (last write: t=1023 -> nxt=0)
    float hj = h2f_(hbuf[0][j]);
    out[(long)B_ * O_ + (long)b * H_ + j] = hj;     // hidden output
    if (j < O_) {                                   // o = h @ W_h2o^T + b_h2o
        float acc = bo[j];
        const float4* wr = (const float4*)(Who + (long)j * H_);
        const u16* hb = hbuf[0];
#pragma unroll 4
        for (int k = 0; k < 128; ++k) {
            float4 wv = wr[k];
            acc += h2f_(hb[4 * k + 0]) * wv.x
                 + h2f_(hb[4 * k + 1]) * wv.y
                 + h2f_(hb[4 * k + 2]) * wv.z
                 + h2f_(hb[4 * k + 3]) * wv.w;
        }
        out[(long)b * O_ + j] = acc;
    }
}

// ---------------------------------------------------------------------------
// Fallback (workspace too small): straightforward fp32, correct but slow.
// ---------------------------------------------------------------------------
__global__ __launch_bounds__(512) void k_fallback(const float* __restrict__ seq,
                                                  const float* __restrict__ W,
                                                  const float* __restrict__ bias,
                                                  const float* __restrict__ Who,
                                                  const float* __restrict__ bo,
                                                  float* __restrict__ out) {
    __shared__ float hb[2][H_];
    int b = blockIdx.x, j = threadIdx.x;
    const float* wrow = W + (long)j * IH_;
    float bj = bias[j];
    hb[0][j] = 0.f;
    __syncthreads();
    for (int t = 0; t < S_; ++t) {
        const float* x = seq + ((long)b * S_ + t) * I_;
        float acc = bj;
        for (int i = 0; i < I_; ++i) acc += x[i] * wrow[i];
        const float* hc = hb[t & 1];
        for (int k = 0; k < H_; ++k) acc += hc[k] * wrow[I_ + k];
        hb[(t & 1) ^ 1][j] = tanh_fast(acc);
        __syncthreads();
    }
    float hj = hb[0][j];
    out[(long)B_ * O_ + (long)b * H_ + j] = hj;
    if (j < O_) {
        float acc = bo[j];
        const float* wr = Who + (long)j * H_;
        for (int k = 0; k < H_; ++k) acc += hb[0][k] * wr[k];
        out[(long)b * O_ + j] = acc;
    }
}

extern "C" void kernel_launch(void* const* d_in, const int* in_sizes, int n_in,
                              void* d_out, int out_size, void* d_ws, size_t ws_size,
                              hipStream_t stream) {
    const float* seq = (const float*)d_in[0];   // (128,1024,256) fp32
    const float* W   = (const float*)d_in[1];   // (512,768) fp32
    const float* bi  = (const float*)d_in[2];   // (512,)
    const float* Who = (const float*)d_in[3];   // (256,512)
    const float* bo  = (const float*)d_in[4];   // (256,)
    float* out = (float*)d_out;                 // 32768 output + 65536 hidden

    const size_t WS_NEED = (size_t)PRE_OFF + (size_t)B_ * S_ * H_ * 2;

    if (ws_size >= WS_NEED) {
        char* ws = (char*)d_ws;
        uint4* wxb4 = (uint4*)(ws + WXB_OFF);
        uint4* whb4 = (uint4*)(ws + WHB_OFF);
        u16*   pre  = (u16*)(ws + PRE_OFF);
        k_convert<<<192, 256, 0, stream>>>(W, wxb4, whb4);
        k_phase1<<<2048, 256, 0, stream>>>(seq, wxb4, bi, pre);
        k_phase2<<<B_, 512, 0, stream>>>(pre, whb4, Who, bo, out);
    } else {
        k_fallback<<<B_, 512, 0, stream>>>(seq, W, bi, Who, bo, out);
    }
}